// Round 9
// baseline (336.456 us; speedup 1.0000x reference)
//
#include <hip/hip_runtime.h>
#include <cmath>

#define TT 1024
#define HH 8
#define KVHN 4

typedef unsigned short u16;

__device__ __forceinline__ float bflo(unsigned u) { return __uint_as_float(u << 16); }
__device__ __forceinline__ float bfhi(unsigned u) { return __uint_as_float(u & 0xffff0000u); }
__device__ __forceinline__ u16 bfr(float f) {
  unsigned u = __float_as_uint(f);
  return (u16)((u + 0x7fffu + ((u >> 16) & 1u)) >> 16);
}

// dot of 8 bf16 (packed in uint4) with 8 f32 at y (16B-aligned)
__device__ __forceinline__ float dot8(uint4 q, const float* __restrict__ y) {
  float4 ya = *reinterpret_cast<const float4*>(y);
  float4 yb = *reinterpret_cast<const float4*>(y + 4);
  return bflo(q.x) * ya.x + bfhi(q.x) * ya.y + bflo(q.y) * ya.z +
         bfhi(q.y) * ya.w + bflo(q.z) * yb.x + bfhi(q.z) * yb.y +
         bflo(q.w) * yb.z + bfhi(q.w) * yb.w;
}

// ---------------------------------------------------------------------------
// K1: QKV projection as tiled GEMM + fused RoPE. (unchanged, proven)
// ---------------------------------------------------------------------------
__global__ __launch_bounds__(256) void qkv_kernel(
    const float* __restrict__ x, const float* __restrict__ cosb,
    const float* __restrict__ sinb, const float* __restrict__ Wq,
    const float* __restrict__ Wk, const float* __restrict__ Wv,
    float* __restrict__ Q, float* __restrict__ Kt, float* __restrict__ Vt) {
  const int bx = blockIdx.x, cy = blockIdx.y;
  const int tid = threadIdx.x;
  const int ti = tid >> 4, tj = tid & 15;
  const int m0 = bx * 64;

  __shared__ float Xs[64][68];
  __shared__ float Ws[64][68];

  const float* Wsel;
  int wstride, wc0;
  if (cy < 8) { Wsel = Wq; wstride = 512; wc0 = cy * 64; }
  else if (cy < 12) { Wsel = Wk; wstride = 256; wc0 = (cy - 8) * 64; }
  else { Wsel = Wv; wstride = 256; wc0 = (cy - 12) * 64; }

  float acc[4][4] = {};

  for (int k0 = 0; k0 < 512; k0 += 64) {
    __syncthreads();
#pragma unroll
    for (int m = 0; m < 4; ++m) {
      int f = m * 256 + tid;
      int rr = f >> 4, dc = (f & 15) * 4;
      *reinterpret_cast<float4*>(&Xs[rr][dc]) =
          *reinterpret_cast<const float4*>(x + (size_t)(m0 + rr) * 512 + k0 + dc);
    }
#pragma unroll
    for (int m = 0; m < 4; ++m) {
      int f = m * 256 + tid;
      int rr = f >> 4, dc = (f & 15) * 4;
      *reinterpret_cast<float4*>(&Ws[rr][dc]) =
          *reinterpret_cast<const float4*>(Wsel + (size_t)(k0 + rr) * wstride + wc0 + dc);
    }
    __syncthreads();

    for (int d = 0; d < 64; d += 4) {
      float4 wv[4];
#pragma unroll
      for (int dd = 0; dd < 4; ++dd)
        wv[dd] = *reinterpret_cast<const float4*>(&Ws[d + dd][4 * tj]);
#pragma unroll
      for (int i2 = 0; i2 < 4; ++i2) {
        float4 xv = *reinterpret_cast<const float4*>(&Xs[4 * ti + i2][d]);
        acc[i2][0] += xv.x * wv[0].x + xv.y * wv[1].x + xv.z * wv[2].x + xv.w * wv[3].x;
        acc[i2][1] += xv.x * wv[0].y + xv.y * wv[1].y + xv.z * wv[2].y + xv.w * wv[3].y;
        acc[i2][2] += xv.x * wv[0].z + xv.y * wv[1].z + xv.z * wv[2].z + xv.w * wv[3].z;
        acc[i2][3] += xv.x * wv[0].w + xv.y * wv[1].w + xv.z * wv[2].w + xv.w * wv[3].w;
      }
    }
  }

  __syncthreads();
#pragma unroll
  for (int i2 = 0; i2 < 4; ++i2) {
    float4 v;
    v.x = acc[i2][0]; v.y = acc[i2][1]; v.z = acc[i2][2]; v.w = acc[i2][3];
    *reinterpret_cast<float4*>(&Xs[4 * ti + i2][4 * tj]) = v;
  }
  __syncthreads();

#pragma unroll
  for (int m = 0; m < 16; ++m) {
    int f = m * 256 + tid;
    int rr = f >> 6, d = f & 63;
    int row = m0 + rr, b = row >> 10, t = row & 1023;
    float val;
    if (cy < 12) {
      int dd = d & 31;
      float c = cosb[t * 32 + dd], s = sinb[t * 32 + dd];
      float v1 = Xs[rr][dd], v2 = Xs[rr][dd + 32];
      val = (d < 32) ? (v1 * c + v2 * s) : (v2 * c - v1 * s);
    } else {
      val = Xs[rr][d];
    }
    if (cy < 8)
      Q[((size_t)(b * HH + cy) * TT + t) * 64 + d] = val;
    else if (cy < 12)
      Kt[((size_t)(b * KVHN + cy - 8) * TT + t) * 64 + d] = val;
    else
      Vt[((size_t)(b * KVHN + cy - 12) * TT + t) * 64 + d] = val;
  }
}

// ---------------------------------------------------------------------------
// K2: tiled causal logits + exp (UNNORMALIZED) -> A (bf16); 1/rowsum -> invs.
// (unchanged, proven)
// ---------------------------------------------------------------------------
__global__ __launch_bounds__(256) void logits_exp_kernel(
    const float* __restrict__ Q, const float* __restrict__ Kt,
    u16* __restrict__ A, float* __restrict__ invs) {
  const int it = blockIdx.x, sys = blockIdx.y;
  const int b = sys >> 3, kvh = (sys & 7) >> 1;
  const int tid = threadIdx.x;
  const int ti = tid >> 4, tj = tid & 15;

  __shared__ float Qt[64][68];
  __shared__ float KtS[64][68];
  __shared__ float red[64][17];

  const float* Qb = Q + ((size_t)sys * TT + it * 64) * 64;
  const float* Kb = Kt + ((size_t)(b * KVHN + kvh) * TT) * 64;
  u16* Aout = A + ((size_t)sys << 20);

#pragma unroll
  for (int m = 0; m < 4; ++m) {
    int f = m * 256 + tid;
    int rr = f >> 4, dc = (f & 15) * 4;
    float4 v = *reinterpret_cast<const float4*>(Qb + (size_t)rr * 64 + dc);
    *reinterpret_cast<float4*>(&Qt[rr][dc]) = v;
  }

  float rs[4] = {0.f, 0.f, 0.f, 0.f};

  for (int jt = 0; jt <= it; ++jt) {
    __syncthreads();
#pragma unroll
    for (int m = 0; m < 4; ++m) {
      int f = m * 256 + tid;
      int rr = f >> 4, dc = (f & 15) * 4;
      float4 v = *reinterpret_cast<const float4*>(
          Kb + (size_t)(jt * 64 + rr) * 64 + dc);
      *reinterpret_cast<float4*>(&KtS[rr][dc]) = v;
    }
    __syncthreads();

    float acc[4][4] = {};
    for (int d = 0; d < 64; d += 4) {
      float4 qv[4], kv[4];
#pragma unroll
      for (int i2 = 0; i2 < 4; ++i2)
        qv[i2] = *reinterpret_cast<const float4*>(&Qt[4 * ti + i2][d]);
#pragma unroll
      for (int j2 = 0; j2 < 4; ++j2)
        kv[j2] = *reinterpret_cast<const float4*>(&KtS[4 * tj + j2][d]);
#pragma unroll
      for (int i2 = 0; i2 < 4; ++i2)
#pragma unroll
        for (int j2 = 0; j2 < 4; ++j2)
          acc[i2][j2] += qv[i2].x * kv[j2].x + qv[i2].y * kv[j2].y +
                         qv[i2].z * kv[j2].z + qv[i2].w * kv[j2].w;
    }

    int Jb = jt * 64 + 4 * tj;
#pragma unroll
    for (int ir = 0; ir < 4; ++ir) {
      int I = it * 64 + 4 * ti + ir;
      float4 ev;
      float e;
      e = (Jb + 0 <= I) ? __expf(acc[ir][0] * 0.125f) : 0.f; rs[ir] += e; ev.x = e;
      e = (Jb + 1 <= I) ? __expf(acc[ir][1] * 0.125f) : 0.f; rs[ir] += e; ev.y = e;
      e = (Jb + 2 <= I) ? __expf(acc[ir][2] * 0.125f) : 0.f; rs[ir] += e; ev.z = e;
      e = (Jb + 3 <= I) ? __expf(acc[ir][3] * 0.125f) : 0.f; rs[ir] += e; ev.w = e;
      uint2 pk;
      pk.x = (unsigned)bfr(ev.x) | ((unsigned)bfr(ev.y) << 16);
      pk.y = (unsigned)bfr(ev.z) | ((unsigned)bfr(ev.w) << 16);
      *reinterpret_cast<uint2*>(Aout + (size_t)I * 1024 + Jb) = pk;
    }
  }

  __syncthreads();
#pragma unroll
  for (int ir = 0; ir < 4; ++ir) red[4 * ti + ir][tj] = rs[ir];
  __syncthreads();
  if (tid < 64) {
    float s = 0.f;
#pragma unroll
    for (int t2 = 0; t2 < 16; ++t2) s += red[tid][t2];
    invs[sys * 1024 + it * 64 + tid] = 1.0f / s;
  }
}

// ---------------------------------------------------------------------------
// K3a: invert each (I + S*L_kk) diagonal block IN PLACE over bf16 A. (unchanged)
// ---------------------------------------------------------------------------
__global__ __launch_bounds__(256) void diaginv_kernel(
    u16* __restrict__ A, const float* __restrict__ invs) {
  const int k = blockIdx.x, sys = blockIdx.y;
  const int tid = threadIdx.x;
  const int r = tid & 63, cq = tid >> 6;

  u16* Ab = A + ((size_t)sys << 20) + (size_t)(k * 64) * 1024 + k * 64;

  __shared__ float Lt[64][65];
  __shared__ float W[64][65];
  __shared__ float sv[64];

#pragma unroll
  for (int m = 0; m < 2; ++m) {
    int f = m * 256 + tid;
    int rr = f >> 3, ch = f & 7;
    uint4 v = *reinterpret_cast<const uint4*>(Ab + (size_t)rr * 1024 + ch * 8);
    float* dst = &Lt[rr][ch * 8];
    dst[0] = bflo(v.x); dst[1] = bfhi(v.x); dst[2] = bflo(v.y); dst[3] = bfhi(v.y);
    dst[4] = bflo(v.z); dst[5] = bfhi(v.z); dst[6] = bflo(v.w); dst[7] = bfhi(v.w);
  }
  if (tid < 64) sv[tid] = invs[sys * 1024 + k * 64 + tid];
#pragma unroll
  for (int c = 0; c < 16; ++c) W[r][cq * 16 + c] = (r == cq * 16 + c) ? 1.f : 0.f;
  __syncthreads();

  for (int r2 = 0; r2 < 64; ++r2) {
    float dinv = 1.0f / (1.0f + sv[r2] * Lt[r2][r2]);
    if (r == r2) {
#pragma unroll
      for (int c = 0; c < 16; ++c) W[r2][cq * 16 + c] *= dinv;
    }
    __syncthreads();
    if (r > r2) {
      float f = sv[r] * Lt[r][r2];
#pragma unroll
      for (int c = 0; c < 16; ++c) W[r][cq * 16 + c] -= f * W[r2][cq * 16 + c];
    }
    __syncthreads();
  }

#pragma unroll
  for (int m = 0; m < 8; ++m) {
    int f = m * 256 + tid;
    int rr = f >> 5, cp = (f & 31) * 2;
    unsigned pk = (unsigned)bfr(W[rr][cp]) | ((unsigned)bfr(W[rr][cp + 1]) << 16);
    *reinterpret_cast<unsigned*>(Ab + (size_t)rr * 1024 + cp) = pk;
  }
}

// ---------------------------------------------------------------------------
// K3b: forward solve, NO A-tile staging. Grid dim3(16 sys, 8 cg), 512 threads.
// Thread (r,c): A rows read DIRECTLY from L2 (8 lanes same-address broadcast);
// only Y-strip / u vectors in LDS. 2 barriers per k-step (32 total).
// ---------------------------------------------------------------------------
__global__ __launch_bounds__(512) void solve_strip_kernel(
    const u16* __restrict__ A, const float* __restrict__ invs,
    const float* __restrict__ Vt, float* __restrict__ Y) {
  const int sys = blockIdx.x, cg = blockIdx.y;
  const int b = sys >> 3, kvh = (sys & 7) >> 1;
  const int tid = threadIdx.x;
  const int r = (tid >> 6) * 8 + ((tid & 63) >> 3);  // 0..63
  const int c = tid & 7;                             // 0..7
  const int c0 = cg * 8;

  const u16* Ab = A + ((size_t)sys << 20);
  const float* Vb = Vt + ((size_t)(b * KVHN + kvh) * TT) * 64;
  float* Yg = Y + (size_t)sys * TT * 64;

  __shared__ float Yt[8][1028];  // [col][row] solved strip
  __shared__ float uT[8][68];

  for (int k = 0; k < 16; ++k) {
    const float sinv = invs[sys * 1024 + k * 64 + r];
    const float v0 = Vb[(size_t)(k * 64 + r) * 64 + c0 + c];
    const u16* Arow = Ab + (size_t)(k * 64 + r) * 1024;

    float a0 = 0.f, a1 = 0.f, a2 = 0.f, a3 = 0.f;
    for (int jt = 0; jt < k; ++jt) {
      const uint4* Aq = reinterpret_cast<const uint4*>(Arow + jt * 64);
      const float* Ya = &Yt[c][jt * 64];
      a0 += dot8(Aq[0], Ya) + dot8(Aq[1], Ya + 8);
      a1 += dot8(Aq[2], Ya + 16) + dot8(Aq[3], Ya + 24);
      a2 += dot8(Aq[4], Ya + 32) + dot8(Aq[5], Ya + 40);
      a3 += dot8(Aq[6], Ya + 48) + dot8(Aq[7], Ya + 56);
    }

    float u = v0 - sinv * ((a0 + a1) + (a2 + a3));
    uT[c][r] = u;
    __syncthreads();  // uT complete (cols span all waves)

    const uint4* Mq = reinterpret_cast<const uint4*>(Arow + k * 64);
    const float* ua = &uT[c][0];
    float y = dot8(Mq[0], ua) + dot8(Mq[1], ua + 8) + dot8(Mq[2], ua + 16) +
              dot8(Mq[3], ua + 24) + dot8(Mq[4], ua + 32) +
              dot8(Mq[5], ua + 40) + dot8(Mq[6], ua + 48) +
              dot8(Mq[7], ua + 56);
    Yt[c][k * 64 + r] = y;
    Yg[(size_t)(k * 64 + r) * 64 + c0 + c] = y;
    __syncthreads();  // Yt[k] published; uT free for next k
  }
}

// ---------------------------------------------------------------------------
// K4: out = x + Y2d @ Wo as tiled GEMM. (unchanged, proven)
// ---------------------------------------------------------------------------
__global__ __launch_bounds__(256) void out_proj_kernel(
    const float* __restrict__ Y, const float* __restrict__ x,
    const float* __restrict__ Wo, float* __restrict__ out) {
  const int bx = blockIdx.x, by = blockIdx.y;
  const int tid = threadIdx.x;
  const int ti = tid >> 4, tj = tid & 15;
  const int m0 = bx * 64, n0 = by * 64;

  __shared__ float Ys[64][68];
  __shared__ float Ws[64][68];

  float acc[4][4] = {};

  for (int k0 = 0; k0 < 512; k0 += 64) {
    const int h = k0 >> 6;
    __syncthreads();
#pragma unroll
    for (int m = 0; m < 4; ++m) {
      int f = m * 256 + tid;
      int rr = f >> 4, dc = (f & 15) * 4;
      int row = m0 + rr, b = row >> 10, t = row & 1023;
      *reinterpret_cast<float4*>(&Ys[rr][dc]) =
          *reinterpret_cast<const float4*>(
              Y + ((size_t)(b * HH + h) * TT + t) * 64 + dc);
    }
#pragma unroll
    for (int m = 0; m < 4; ++m) {
      int f = m * 256 + tid;
      int rr = f >> 4, dc = (f & 15) * 4;
      *reinterpret_cast<float4*>(&Ws[rr][dc]) =
          *reinterpret_cast<const float4*>(Wo + (size_t)(k0 + rr) * 512 + n0 + dc);
    }
    __syncthreads();

    for (int d = 0; d < 64; d += 4) {
      float4 wv[4];
#pragma unroll
      for (int dd = 0; dd < 4; ++dd)
        wv[dd] = *reinterpret_cast<const float4*>(&Ws[d + dd][4 * tj]);
#pragma unroll
      for (int i2 = 0; i2 < 4; ++i2) {
        float4 xv = *reinterpret_cast<const float4*>(&Ys[4 * ti + i2][d]);
        acc[i2][0] += xv.x * wv[0].x + xv.y * wv[1].x + xv.z * wv[2].x + xv.w * wv[3].x;
        acc[i2][1] += xv.x * wv[0].y + xv.y * wv[1].y + xv.z * wv[2].y + xv.w * wv[3].y;
        acc[i2][2] += xv.x * wv[0].z + xv.y * wv[1].z + xv.z * wv[2].z + xv.w * wv[3].z;
        acc[i2][3] += xv.x * wv[0].w + xv.y * wv[1].w + xv.z * wv[2].w + xv.w * wv[3].w;
      }
    }
  }

#pragma unroll
  for (int i2 = 0; i2 < 4; ++i2) {
    size_t row = (size_t)(m0 + 4 * ti + i2);
    float4 xr = *reinterpret_cast<const float4*>(x + row * 512 + n0 + 4 * tj);
    float4 v;
    v.x = xr.x + acc[i2][0]; v.y = xr.y + acc[i2][1];
    v.z = xr.z + acc[i2][2]; v.w = xr.w + acc[i2][3];
    *reinterpret_cast<float4*>(out + row * 512 + n0 + 4 * tj) = v;
  }
}

// ---------------------------------------------------------------------------
extern "C" void kernel_launch(void* const* d_in, const int* in_sizes, int n_in,
                              void* d_out, int out_size, void* d_ws,
                              size_t ws_size, hipStream_t stream) {
  (void)in_sizes; (void)n_in; (void)out_size; (void)ws_size;
  const float* x = (const float*)d_in[0];
  const float* cosb = (const float*)d_in[1];
  const float* sinb = (const float*)d_in[2];
  const float* Wq = (const float*)d_in[3];
  const float* Wk = (const float*)d_in[4];
  const float* Wv = (const float*)d_in[5];
  const float* Wo = (const float*)d_in[6];
  float* out = (float*)d_out;

  float* ws = (float*)d_ws;
  float* Q = ws;                        // 1,048,576 f
  float* Kt = Q + (size_t)1048576;      //   524,288 f
  float* Vt = Kt + (size_t)524288;      //   524,288 f
  float* Yb = Vt + (size_t)524288;      // 1,048,576 f
  float* invs = Yb + (size_t)1048576;   //    16,384 f
  u16* A = (u16*)(invs + 16384);        // 16,777,216 bf16 = 32 MB

  qkv_kernel<<<dim3(32, 16), 256, 0, stream>>>(x, cosb, sinb, Wq, Wk, Wv, Q, Kt, Vt);
  logits_exp_kernel<<<dim3(16, 16), 256, 0, stream>>>(Q, Kt, A, invs);
  diaginv_kernel<<<dim3(16, 16), 256, 0, stream>>>(A, invs);
  solve_strip_kernel<<<dim3(16, 8), 512, 0, stream>>>(A, invs, Vt, Yb);
  out_proj_kernel<<<dim3(32, 8), 256, 0, stream>>>(Yb, x, Wo, out);
}